// Round 1
// baseline (120.551 us; speedup 1.0000x reference)
//
#include <hip/hip_runtime.h>
#include <math.h>

#define NT 32768
#define SCALEF 4.0f

// broadcast-readlane: value of v in lane l, as SGPR (1 VALU instr), feeds FMA src
__device__ __forceinline__ float rl(float v, int l) {
    return __int_as_float(__builtin_amdgcn_readlane(__float_as_int(v), l));
}

__device__ __forceinline__ float frame_val(const float* __restrict__ obs,
                                           const float* __restrict__ pred,
                                           int F, int d) {
    return (F < 9) ? obs[F * (NT * 2) + d] : pred[(F - 9) * (NT * 2) + d];
}

__launch_bounds__(512, 2)
__global__ void lstm_disc_kernel(const float* __restrict__ observed,
                                 const float* __restrict__ prediction,
                                 const float* __restrict__ W_emb,
                                 const float* __restrict__ b_emb,
                                 const float* __restrict__ W_ih,
                                 const float* __restrict__ W_hh,
                                 const float* __restrict__ b_ih,
                                 const float* __restrict__ b_hh,
                                 const float* __restrict__ W1,
                                 const float* __restrict__ b1,
                                 const float* __restrict__ W2,
                                 const float* __restrict__ b2,
                                 const float* __restrict__ W3,
                                 const float* __restrict__ b3,
                                 float* __restrict__ out)
{
    const int tid  = (int)threadIdx.x;   // == gate index j in [0,512)
    const int lane = tid & 63;

    __shared__ float xs[21][64];      // per-step input embedding vectors
    __shared__ float gx[21][512];     // h-independent gate pre-activations
    __shared__ float velx[21], vely[21], maskf[21];
    __shared__ float gact[512];       // activated gates of current step
    __shared__ float hbuf[128];
    __shared__ float mlp1[64];
    __shared__ float mlp2[32];

    // ---- (a) velocities + visibility masks for track 0 ----
    if (tid < 20) {
        float ax = frame_val(observed, prediction, tid,     0);
        float ay = frame_val(observed, prediction, tid,     1);
        float bx = frame_val(observed, prediction, tid + 1, 0);
        float by = frame_val(observed, prediction, tid + 1, 1);
        unsigned ua = __float_as_uint(ax) & 0x7fffffffu;
        unsigned ub = __float_as_uint(bx) & 0x7fffffffu;
        bool m = !((ua > 0x7f800000u) || (ub > 0x7f800000u));   // NaN-safe, fast-math-proof
        maskf[tid + 1] = m ? 1.0f : 0.0f;
        velx[tid + 1]  = m ? (bx - ax) * SCALEF : 0.0f;
        vely[tid + 1]  = m ? (by - ay) * SCALEF : 0.0f;
    }
    if (tid == 20) { maskf[0] = 1.0f; velx[0] = 0.0f; vely[0] = 0.0f; }
    __syncthreads();

    // ---- (b) build x vectors: xs[0] = start tag one-hot, xs[1..20] = relu(vel*S @ W_emb^T + b) ++ [0,0]
    for (int idx = tid; idx < 21 * 64; idx += 512) {
        int s = idx >> 6, e = idx & 63;
        float v;
        if (s == 0)       v = (e == 62) ? 1.0f : 0.0f;
        else if (e < 62)  v = fmaxf(velx[s] * W_emb[2 * e] + vely[s] * W_emb[2 * e + 1] + b_emb[e], 0.0f);
        else              v = 0.0f;
        xs[s][e] = v;
    }
    __syncthreads();

    // uniform step mask bits
    unsigned mbits = 0;
    #pragma unroll
    for (int s = 0; s < 21; ++s) mbits |= (maskf[s] != 0.0f ? 1u : 0u) << s;

    // ---- (c) gx[s][j] = x_s . W_ih[j] + b_ih[j] + b_hh[j]  (h-independent, fully parallel)
    float wih[64];
    #pragma unroll
    for (int q = 0; q < 16; ++q) {
        float4 w = *reinterpret_cast<const float4*>(W_ih + tid * 64 + 4 * q);
        wih[4*q] = w.x; wih[4*q+1] = w.y; wih[4*q+2] = w.z; wih[4*q+3] = w.w;
    }
    const float bias = b_ih[tid] + b_hh[tid];
    gx[0][tid] = bias + wih[62];                       // tag one-hot at position 62
    for (int s = 1; s < 21; ++s) {
        float xc = xs[s][lane];                        // lane-held column of x_s
        float acc = bias;
        #pragma unroll
        for (int e = 0; e < 62; ++e) acc += rl(xc, e) * wih[e];   // xs[s][62..63]==0
        gx[s][tid] = acc;
    }

    // ---- (d) serial recurrence: register-resident W_hh row, readlane h-broadcast
    float whh[128];
    #pragma unroll
    for (int q = 0; q < 32; ++q) {
        float4 w = *reinterpret_cast<const float4*>(W_hh + tid * 128 + 4 * q);
        whh[4*q] = w.x; whh[4*q+1] = w.y; whh[4*q+2] = w.z; whh[4*q+3] = w.w;
    }
    __syncthreads();                                    // gx complete

    float hlo = 0.0f, hhi = 0.0f, creg = 0.0f;          // h[lane], h[64+lane]; c[tid] valid for tid<128
    const int gtype = tid >> 7;                         // 0=i 1=f 2=g 3=o

    for (int s = 0; s < 21; ++s) {
        if (mbits & (1u << s)) {                        // uniform branch (no NaN frame -> always taken)
            float acc = gx[s][tid];
            #pragma unroll
            for (int k = 0; k < 64; ++k) acc += rl(hlo, k) * whh[k];
            #pragma unroll
            for (int k = 0; k < 64; ++k) acc += rl(hhi, k) * whh[64 + k];
            float a = (gtype == 2) ? tanhf(acc) : 1.0f / (1.0f + expf(-acc));
            gact[tid] = a;
            __syncthreads();
            if (tid < 128) {
                float gi = gact[tid], gf = gact[128 + tid], gg = gact[256 + tid], go = gact[384 + tid];
                creg = gf * creg + gi * gg;
                hbuf[tid] = go * tanhf(creg);
            }
            __syncthreads();
            hlo = hbuf[lane];
            hhi = hbuf[64 + lane];
        }
    }

    // ---- (e) classifier MLP on h (track 0) ----
    if (tid < 64) {
        float a = b1[tid];
        #pragma unroll
        for (int k = 0; k < 128; ++k) a += W1[tid * 128 + k] * hbuf[k];
        mlp1[tid] = fmaxf(a, 0.0f);
    }
    __syncthreads();
    if (tid < 32) {
        float a = b2[tid];
        #pragma unroll
        for (int k = 0; k < 64; ++k) a += W2[tid * 64 + k] * mlp1[k];
        mlp2[tid] = fmaxf(a, 0.0f);
    }
    __syncthreads();
    if (tid == 0) {
        float a = b3[0];
        #pragma unroll
        for (int k = 0; k < 32; ++k) a += W3[k] * mlp2[k];
        out[0] = fmaxf(a, 0.0f);
    }
}

extern "C" void kernel_launch(void* const* d_in, const int* in_sizes, int n_in,
                              void* d_out, int out_size, void* d_ws, size_t ws_size,
                              hipStream_t stream) {
    lstm_disc_kernel<<<1, 512, 0, stream>>>(
        (const float*)d_in[0],  (const float*)d_in[1],
        (const float*)d_in[2],  (const float*)d_in[3],
        (const float*)d_in[4],  (const float*)d_in[5],
        (const float*)d_in[6],  (const float*)d_in[7],
        (const float*)d_in[8],  (const float*)d_in[9],
        (const float*)d_in[10], (const float*)d_in[11],
        (const float*)d_in[12], (const float*)d_in[13],
        (float*)d_out);
}